// Round 13
// baseline (725.251 us; speedup 1.0000x reference)
//
#include <hip/hip_runtime.h>
#include <math.h>
#include <stdint.h>

#define EMB 128
#define HID 256
#define ED 16
#define NGRAPH 512
#define NLAYER 3
#define NPW 8            // nodes per wave in k_agg (contiguous chunk)

typedef unsigned short ushort_t;
typedef __attribute__((ext_vector_type(8))) short short8;
typedef __attribute__((ext_vector_type(4))) float fx4;
typedef __attribute__((ext_vector_type(4))) unsigned int uint4v;

__device__ __forceinline__ ushort_t f2b(float f){
  unsigned int u = __builtin_bit_cast(unsigned int, f);
  unsigned int r = u + 0x7FFFu + ((u >> 16) & 1u);
  return (ushort_t)(r >> 16);
}
__device__ __forceinline__ float b2f(ushort_t u){
  return __builtin_bit_cast(float, ((unsigned int)u) << 16);
}
__device__ __forceinline__ float blo(unsigned int u){
  return __builtin_bit_cast(float, u << 16);
}
__device__ __forceinline__ float bhi(unsigned int u){
  return __builtin_bit_cast(float, u & 0xFFFF0000u);
}

// packed bf16x2 dot with f32 accumulate: c += a.lo*b.lo + a.hi*b.hi
__device__ __forceinline__ float dot2b(unsigned int a, unsigned int b, float c){
  float r = c;
  asm("v_dot2_f32_bf16 %0, %1, %2, %0" : "+v"(r) : "v"(a), "v"(b));
  return r;
}

// 16-elem bf16 dot for two output channels from 2 packed uint4v
__device__ __forceinline__ float2 dot16(uint4v u0, uint4v u1,
                                        const unsigned int* wp0, const unsigned int* wp1,
                                        float be0, float be1){
  unsigned int uu[8] = {u0[0], u0[1], u0[2], u0[3], u1[0], u1[1], u1[2], u1[3]};
  float e0 = be0, e1 = be1;
  #pragma unroll
  for (int k = 0; k < 8; k++){
    e0 = dot2b(uu[k], wp0[k], e0);
    e1 = dot2b(uu[k], wp1[k], e1);
  }
  return make_float2(e0, e1);
}

// ---- init virtual node (broadcast vn_emb row) ----
__global__ void k_init_vn(float* __restrict__ vn, const float* __restrict__ vn_emb){
  int idx = blockIdx.x * 256 + threadIdx.x;            // NGRAPH*EMB threads
  vn[idx] = vn_emb[idx & (EMB - 1)];
}

// ---- pre-transpose MLP weights f32 -> bf16 [N][K] for MFMA B-operand ----
__global__ void k_transw(const float* __restrict__ w1, const float* __restrict__ w2,
                         ushort_t* __restrict__ w1t, ushort_t* __restrict__ w2t){
  int idx = blockIdx.x * 256 + threadIdx.x;
  if (idx >= NLAYER * EMB * HID) return;
  int l = idx / (EMB * HID);
  int r = idx % (EMB * HID);
  { int k = r / HID, n = r % HID; w1t[(l * HID + n) * EMB + k] = f2b(w1[idx]); }
  { int k = r / EMB, n = r % EMB; w2t[(l * EMB + n) * HID + k] = f2b(w2[idx]); }
}

// ---- CSR build: count + rank ----
__global__ void k_count(const int* __restrict__ dst, int* __restrict__ counts,
                        int* __restrict__ rankv, int E){
  int e = blockIdx.x * 256 + threadIdx.x;
  if (e >= E) return;
  rankv[e] = atomicAdd(&counts[dst[e]], 1);
}

// ---- 3-kernel exclusive scan over counts[N] -> offs[N] ----
__global__ void k_scanA(const int* __restrict__ counts, int* __restrict__ offs,
                        int* __restrict__ bsum, int N){
  __shared__ int sdata[256];
  int t = threadIdx.x;
  int base = blockIdx.x * 2048 + t * 8;
  int v[8]; int s = 0;
  #pragma unroll
  for (int j = 0; j < 8; j++){
    int idx = base + j;
    v[j] = (idx < N) ? counts[idx] : 0;
    s += v[j];
  }
  sdata[t] = s; __syncthreads();
  for (int off = 1; off < 256; off <<= 1){
    int x = (t >= off) ? sdata[t - off] : 0;
    __syncthreads();
    sdata[t] += x;
    __syncthreads();
  }
  int incl = sdata[t];
  int run = incl - s;   // exclusive prefix of this thread's chunk
  #pragma unroll
  for (int j = 0; j < 8; j++){
    int idx = base + j;
    if (idx < N) offs[idx] = run;
    run += v[j];
  }
  if (t == 255) bsum[blockIdx.x] = incl;
}

__global__ void k_scanB(const int* __restrict__ bsum, int* __restrict__ boff, int nb){
  __shared__ int sdata[256];
  int t = threadIdx.x;
  int v = (t < nb) ? bsum[t] : 0;
  sdata[t] = v; __syncthreads();
  for (int off = 1; off < 256; off <<= 1){
    int x = (t >= off) ? sdata[t - off] : 0;
    __syncthreads();
    sdata[t] += x;
    __syncthreads();
  }
  if (t < nb) boff[t] = sdata[t] - v;
}

__global__ void k_scanC(int* __restrict__ offs, const int* __restrict__ boff, int N, int E){
  int i = blockIdx.x * 256 + threadIdx.x;
  if (i < N) offs[i] += boff[i >> 11];
  else if (i == N) offs[N] = E;
}

// ---- CSR reorder: ea2[pos] = bf16(edge_attr[e]); srcs[pos] = src[e] ----
__global__ void k_reorder(const float* __restrict__ ea, const int* __restrict__ src,
                          const int* __restrict__ dst, const int* __restrict__ rankv,
                          const int* __restrict__ offs, ushort_t* __restrict__ ea2,
                          int* __restrict__ srcs, int E){
  int e = blockIdx.x * 256 + threadIdx.x;
  if (e >= E) return;
  int pos = offs[dst[e]] + rankv[e];
  srcs[pos] = src[e];
  const float4* p = (const float4*)(ea + (size_t)e * ED);
  float4 f0 = p[0], f1 = p[1], f2 = p[2], f3 = p[3];
  float f[ED] = {f0.x, f0.y, f0.z, f0.w, f1.x, f1.y, f1.z, f1.w,
                 f2.x, f2.y, f2.z, f2.w, f3.x, f3.y, f3.z, f3.w};
  unsigned int u[8];
  #pragma unroll
  for (int k = 0; k < 8; k++)
    u[k] = (unsigned int)f2b(f[2 * k]) | ((unsigned int)f2b(f[2 * k + 1]) << 16);
  uint4* q = (uint4*)(ea2 + (size_t)pos * ED);
  q[0] = make_uint4(u[0], u[1], u[2], u[3]);
  q[1] = make_uint4(u[4], u[5], u[6], u[7]);
}

// ---- layer-0 h_in = bf16(in_feat + vn[batch]) -> hb only ----
__global__ void k_hin(const float* __restrict__ h, const int* __restrict__ batch,
                      const float* __restrict__ vn, ushort_t* __restrict__ hb, int N){
  int idx = blockIdx.x * 256 + threadIdx.x;
  if (idx >= N * 32) return;
  int node = idx >> 5;
  int c = (idx & 31) * 4;
  float4 hv = *(const float4*)(h + (size_t)node * EMB + c);
  int b = batch[node];
  float4 v = *(const float4*)(vn + b * EMB + c);
  uint2 ob;
  ob.x = (unsigned int)f2b(hv.x + v.x) | ((unsigned int)f2b(hv.y + v.y) << 16);
  ob.y = (unsigned int)f2b(hv.z + v.z) | ((unsigned int)f2b(hv.w + v.w) << 16);
  *(uint2*)(hb + (size_t)node * EMB + c) = ob;
}

// ---- pull-style GIN aggregation (R7-proven pipeline) + fused vt accumulation.
//      Contiguous NPW-node chunk per wave, flat edge stream with node-boundary
//      flush, software-pipelined (srcs 2 groups ahead, gathers 1 group ahead).
//      vt fusion uses k_vt's proven pattern: per-lane running sum over the
//      contiguous same-graph node run, wave-uniform boundary + final atomics
//      (~1.8M total — NOT R9's 12.8M per-node atomics). Saves k_vt's full hb
//      re-read (26 µs serial + 51 MB). vt must be memset-zeroed BEFORE launch.
//      z0 = bf16(h_in + sum_{e->node} relu(h_in[src]+edge_emb)) ----
__global__ __launch_bounds__(256) void k_agg(const ushort_t* __restrict__ hb,
                      const ushort_t* __restrict__ ea2,
                      const int* __restrict__ srcs, const int* __restrict__ offs,
                      const float* __restrict__ We, const float* __restrict__ be,
                      ushort_t* __restrict__ z0, float* __restrict__ vt,
                      const int* __restrict__ batch, int dovt, int N){
  int lane = threadIdx.x & 63;
  int wid = (blockIdx.x * blockDim.x + threadIdx.x) >> 6;
  int n0 = wid * NPW;
  if (n0 >= N) return;
  int nn = N - n0; if (nn > NPW) nn = NPW;
  int c0 = lane * 2;

  // pack edge-encoder weight columns c0, c0+1 as bf16 pairs (k-major pairs)
  unsigned int wp0[8], wp1[8];
  #pragma unroll
  for (int k = 0; k < 8; k++){
    wp0[k] = (unsigned int)f2b(We[(2 * k) * EMB + c0])
           | ((unsigned int)f2b(We[(2 * k + 1) * EMB + c0]) << 16);
    wp1[k] = (unsigned int)f2b(We[(2 * k) * EMB + c0 + 1])
           | ((unsigned int)f2b(We[(2 * k + 1) * EMB + c0 + 1]) << 16);
  }
  float be0 = be[c0], be1 = be[c0 + 1];

  int j    = offs[n0];
  int cend = offs[n0 + 1];
  int jend = offs[n0 + nn];
  int ni = 0;
  unsigned int hn = *(const unsigned int*)(hb + (size_t)n0 * EMB + c0);
  float ax = 0.f, ay = 0.f;
  // fused-vt state (k_vt pattern: boundary + final atomics, wave-uniform g)
  int curg = dovt ? batch[n0] : 0;
  float vax = 0.f, vay = 0.f;

  // flush: when j reaches current node's end, write z0 row(s) and accumulate
  // this node's h_in into the running per-graph sum; handles empty nodes
  auto flush = [&](){
    while (j == cend && ni < nn){
      float r0 = blo(hn) + ax, r1 = bhi(hn) + ay;
      unsigned int outv = (unsigned int)f2b(r0) | ((unsigned int)f2b(r1) << 16);
      *(unsigned int*)(z0 + (size_t)(n0 + ni) * EMB + c0) = outv;
      if (dovt){
        int g = batch[n0 + ni];                  // wave-uniform (sorted batch)
        if (g != curg){
          atomicAdd(&vt[curg * EMB + c0], vax);
          atomicAdd(&vt[curg * EMB + c0 + 1], vay);
          vax = 0.f; vay = 0.f; curg = g;
        }
        vax += blo(hn); vay += bhi(hn);
      }
      ni++;
      if (ni < nn){
        hn = *(const unsigned int*)(hb + (size_t)(n0 + ni) * EMB + c0);
        cend = offs[n0 + ni + 1];
        ax = 0.f; ay = 0.f;
      }
    }
  };

  auto do1 = [&](unsigned int g){
    const uint4v* p = (const uint4v*)(ea2 + (size_t)j * ED);
    uint4v u0 = p[0], u1 = p[1];
    float2 m = dot16(u0, u1, wp0, wp1, be0, be1);
    ax += fmaxf(blo(g) + m.x, 0.f);
    ay += fmaxf(bhi(g) + m.y, 0.f);
    j++; flush();
  };

  auto do4 = [&](unsigned int gA, unsigned int gB, unsigned int gC, unsigned int gD){
    const uint4v* p = (const uint4v*)(ea2 + (size_t)j * ED);
    uint4v uA0 = p[0], uA1 = p[1];
    uint4v uB0 = p[2], uB1 = p[3];
    uint4v uC0 = p[4], uC1 = p[5];
    uint4v uD0 = p[6], uD1 = p[7];
    float2 mA = dot16(uA0, uA1, wp0, wp1, be0, be1);
    float2 mB = dot16(uB0, uB1, wp0, wp1, be0, be1);
    float2 mC = dot16(uC0, uC1, wp0, wp1, be0, be1);
    float2 mD = dot16(uD0, uD1, wp0, wp1, be0, be1);
    ax += fmaxf(blo(gA) + mA.x, 0.f);  ay += fmaxf(bhi(gA) + mA.y, 0.f);  j++; flush();
    ax += fmaxf(blo(gB) + mB.x, 0.f);  ay += fmaxf(bhi(gB) + mB.y, 0.f);  j++; flush();
    ax += fmaxf(blo(gC) + mC.x, 0.f);  ay += fmaxf(bhi(gC) + mC.y, 0.f);  j++; flush();
    ax += fmaxf(blo(gD) + mD.x, 0.f);  ay += fmaxf(bhi(gD) + mD.y, 0.f);  j++; flush();
  };

  flush();   // leading empty nodes

  if (j + 8 <= jend){
    // prologue: gathers for group j in flight, srcs for group j+4 in regs
    int sA = srcs[j],     sB = srcs[j + 1], sC = srcs[j + 2], sD = srcs[j + 3];
    int nA = srcs[j + 4], nB = srcs[j + 5], nC = srcs[j + 6], nD = srcs[j + 7];
    unsigned int gA = *(const unsigned int*)(hb + (size_t)sA * EMB + c0);
    unsigned int gB = *(const unsigned int*)(hb + (size_t)sB * EMB + c0);
    unsigned int gC = *(const unsigned int*)(hb + (size_t)sC * EMB + c0);
    unsigned int gD = *(const unsigned int*)(hb + (size_t)sD * EMB + c0);

    while (j + 12 <= jend){
      // current group's ea2 (consumed this iteration) — issue first
      const uint4v* p = (const uint4v*)(ea2 + (size_t)j * ED);
      uint4v uA0 = p[0], uA1 = p[1];
      uint4v uB0 = p[2], uB1 = p[3];
      uint4v uC0 = p[4], uC1 = p[5];
      uint4v uD0 = p[6], uD1 = p[7];
      // prefetch next group's gathers + next-next srcs (stay outstanding across
      // this iteration's compute)
      unsigned int hA = *(const unsigned int*)(hb + (size_t)nA * EMB + c0);
      unsigned int hB = *(const unsigned int*)(hb + (size_t)nB * EMB + c0);
      unsigned int hC = *(const unsigned int*)(hb + (size_t)nC * EMB + c0);
      unsigned int hD = *(const unsigned int*)(hb + (size_t)nD * EMB + c0);
      int tA = srcs[j + 8], tB = srcs[j + 9], tC = srcs[j + 10], tD = srcs[j + 11];
      // compute + consume current group
      float2 mA = dot16(uA0, uA1, wp0, wp1, be0, be1);
      float2 mB = dot16(uB0, uB1, wp0, wp1, be0, be1);
      float2 mC = dot16(uC0, uC1, wp0, wp1, be0, be1);
      float2 mD = dot16(uD0, uD1, wp0, wp1, be0, be1);
      ax += fmaxf(blo(gA) + mA.x, 0.f);  ay += fmaxf(bhi(gA) + mA.y, 0.f);  j++; flush();
      ax += fmaxf(blo(gB) + mB.x, 0.f);  ay += fmaxf(bhi(gB) + mB.y, 0.f);  j++; flush();
      ax += fmaxf(blo(gC) + mC.x, 0.f);  ay += fmaxf(bhi(gC) + mC.y, 0.f);  j++; flush();
      ax += fmaxf(blo(gD) + mD.x, 0.f);  ay += fmaxf(bhi(gD) + mD.y, 0.f);  j++; flush();
      gA = hA; gB = hB; gC = hC; gD = hD;
      nA = tA; nB = tB; nC = tC; nD = tD;
    }
    // drain: group at j (gathers gA..gD), then group at j+4 (srcs nA..nD)
    do4(gA, gB, gC, gD);
    gA = *(const unsigned int*)(hb + (size_t)nA * EMB + c0);
    gB = *(const unsigned int*)(hb + (size_t)nB * EMB + c0);
    gC = *(const unsigned int*)(hb + (size_t)nC * EMB + c0);
    gD = *(const unsigned int*)(hb + (size_t)nD * EMB + c0);
    do4(gA, gB, gC, gD);
  }
  while (j < jend){
    int s = srcs[j];
    unsigned int g = *(const unsigned int*)(hb + (size_t)s * EMB + c0);
    do1(g);
  }
  // final vt flush for this wave's chunk
  if (dovt){
    atomicAdd(&vt[curg * EMB + c0], vax);
    atomicAdd(&vt[curg * EMB + c0 + 1], vay);
  }
}

// ---- fused MLP (R7-proven 16-row tiles), register-resident weights,
// grid-stride, cross-tile software pipeline: next-tile A prefetched during
// GEMM1; epilogue operands prefetched before the barrier; vn gathers under
// GEMM2. __launch_bounds__(256,2): weights need 128 VGPRs — forcing 4/CU
// spills (R6); 32-row tiles also spill (R10: compiler capped 128 VGPR).
// ts stride 266 (odd word count) — R12 neutral but harmless; kept.
// v = bn(relu(z0@W1+b1)@W2+b2)(+relu) + h_in(bf16 hb) [+ vn_next[batch]]
// l<2:  write hb (bf16) only.   l==2: write d_out (f32) only. ----
__global__ __launch_bounds__(256, 2) void k_mlp(const ushort_t* __restrict__ A,
                                                const ushort_t* __restrict__ w1t,
                                                const float* __restrict__ b1,
                                                const ushort_t* __restrict__ w2t,
                                                const float* __restrict__ b2,
                                                const float* __restrict__ gamma,
                                                const float* __restrict__ beta,
                                                const ushort_t* __restrict__ hb_in,
                                                const int* __restrict__ batch,
                                                const float* __restrict__ vn_next,
                                                ushort_t* __restrict__ hb_out,
                                                float* __restrict__ fout,
                                                float inv, int last, int ntiles, int N){
  __shared__ ushort_t ts[2][16][266];   // double-buffered hidden tile, 1 barrier/tile
  int w = threadIdx.x >> 6, lane = threadIdx.x & 63;
  int m = lane & 15, q = lane >> 4;

  // ---- preload this wave's weight fragments (once per block) ----
  short8 w1f[4][4];   // [k-step][col-tile], cols w*64 + t*16 + m
  #pragma unroll
  for (int kk = 0; kk < 4; kk++)
    #pragma unroll
    for (int t = 0; t < 4; t++)
      w1f[kk][t] = *(const short8*)(w1t + (size_t)(w * 64 + t * 16 + m) * EMB + kk * 32 + q * 8);
  short8 w2f[8][2];   // cols w*32 + t*16 + m
  #pragma unroll
  for (int kk = 0; kk < 8; kk++)
    #pragma unroll
    for (int t = 0; t < 2; t++)
      w2f[kk][t] = *(const short8*)(w2t + (size_t)(w * 32 + t * 16 + m) * HID + kk * 32 + q * 8);

  float bv1[4], bv2[2], sc2[2], bt2[2];
  #pragma unroll
  for (int t = 0; t < 4; t++) bv1[t] = b1[w * 64 + t * 16 + m];
  #pragma unroll
  for (int t = 0; t < 2; t++){
    int c = w * 32 + t * 16 + m;
    bv2[t] = b2[c]; sc2[t] = gamma[c] * inv; bt2[t] = beta[c];
  }

  int tile = blockIdx.x;
  if (tile >= ntiles) return;
  // prologue: A fragments for first tile
  short8 a_cur[4];
  #pragma unroll
  for (int kk = 0; kk < 4; kk++)
    a_cur[kk] = *(const short8*)(A + (size_t)(tile * 16 + m) * EMB + kk * 32 + q * 8);

  int p = 0;
  for (; tile < ntiles; tile += gridDim.x, p ^= 1){
    int row_base = tile * 16;
    // ---- GEMM1: [16,128] @ [128,256] -> hidden tile (LDS) ----
    fx4 acc[4];
    #pragma unroll
    for (int t = 0; t < 4; t++) acc[t] = fx4{0.f, 0.f, 0.f, 0.f};
    #pragma unroll
    for (int kk = 0; kk < 4; kk++){
      #pragma unroll
      for (int t = 0; t < 4; t++)
        acc[t] = __builtin_amdgcn_mfma_f32_16x16x32_bf16(a_cur[kk], w1f[kk][t], acc[t], 0, 0, 0);
    }
    // prefetch next tile's A fragments (hidden under LDS write + barrier + GEMM2)
    {
      int nt = tile + gridDim.x;
      int nb = (nt < ntiles) ? nt * 16 : 0;
      #pragma unroll
      for (int kk = 0; kk < 4; kk++)
        a_cur[kk] = *(const short8*)(A + (size_t)(nb + m) * EMB + kk * 32 + q * 8);
    }
    // prefetch epilogue operands (independent of LDS)
    int b_r[4]; ushort_t h_r[4][2];
    #pragma unroll
    for (int i = 0; i < 4; i++){
      int r = row_base + q * 4 + i;
      if (r >= N) r = N - 1;            // safety clamp (no-op when N % 16 == 0)
      b_r[i] = last ? 0 : batch[r];
      #pragma unroll
      for (int t = 0; t < 2; t++)
        h_r[i][t] = hb_in[(size_t)r * EMB + w * 32 + t * 16 + m];
    }
    #pragma unroll
    for (int t = 0; t < 4; t++){
      int c = w * 64 + t * 16 + m;
      #pragma unroll
      for (int i = 0; i < 4; i++)
        ts[p][q * 4 + i][c] = f2b(fmaxf(acc[t][i] + bv1[t], 0.f));
    }
    __syncthreads();
    // vn gathers issued now, consumed after GEMM2
    float vnv[4][2];
    if (!last){
      #pragma unroll
      for (int i = 0; i < 4; i++)
        #pragma unroll
        for (int t = 0; t < 2; t++)
          vnv[i][t] = vn_next[b_r[i] * EMB + w * 32 + t * 16 + m];
    }
    // ---- GEMM2: [16,256] @ [256,128] + epilogue ----
    fx4 acc2[2];
    #pragma unroll
    for (int t = 0; t < 2; t++) acc2[t] = fx4{0.f, 0.f, 0.f, 0.f};
    #pragma unroll
    for (int kk = 0; kk < 8; kk++){
      short8 a = *(const short8*)(&ts[p][m][kk * 32 + q * 8]);
      #pragma unroll
      for (int t = 0; t < 2; t++)
        acc2[t] = __builtin_amdgcn_mfma_f32_16x16x32_bf16(a, w2f[kk][t], acc2[t], 0, 0, 0);
    }
    #pragma unroll
    for (int i = 0; i < 4; i++){
      int r = row_base + q * 4 + i;
      if (r >= N) continue;             // safety (no-op when N % 16 == 0)
      #pragma unroll
      for (int t = 0; t < 2; t++){
        int c = w * 32 + t * 16 + m;
        float v = acc2[t][i] + bv2[t];
        v = v * sc2[t] + bt2[t];
        if (!last) v = fmaxf(v, 0.f);                       // inner-layer relu
        v += b2f(h_r[i][t]);                                // residual (prefetched)
        if (!last){
          v += vnv[i][t];                                   // next layer's vn add
          hb_out[(size_t)r * EMB + c] = f2b(v);
        } else {
          fout[(size_t)r * EMB + c] = v;
        }
      }
    }
  }
}

// ---- vn MLP: vn_next = vn_cur + relu(bn1(relu(bn0((vt+vn)@w1+b1))@w2+b2)) ----
__global__ void k_vnmlp(const float* __restrict__ vt,
                        const float* __restrict__ w1, const float* __restrict__ b1,
                        const float* __restrict__ g1, const float* __restrict__ be1,
                        const float* __restrict__ w2, const float* __restrict__ b2,
                        const float* __restrict__ g2, const float* __restrict__ be2,
                        const float* __restrict__ vnc, float* __restrict__ vnn, float inv){
  __shared__ float vs[EMB];
  __shared__ float ms[HID];
  int g = blockIdx.x, t = threadIdx.x;   // 256 threads
  if (t < EMB) vs[t] = vt[g * EMB + t] + vnc[g * EMB + t];
  __syncthreads();
  float acc = b1[t];
  #pragma unroll 4
  for (int k = 0; k < EMB; k++) acc = fmaf(vs[k], w1[k * HID + t], acc);
  acc = acc * (g1[t] * inv) + be1[t];
  ms[t] = fmaxf(acc, 0.f);
  __syncthreads();
  if (t < EMB){
    float a2 = b2[t];
    #pragma unroll 4
    for (int k = 0; k < HID; k++) a2 = fmaf(ms[k], w2[k * EMB + t], a2);
    a2 = a2 * (g2[t] * inv) + be2[t];
    vnn[g * EMB + t] = vnc[g * EMB + t] + fmaxf(a2, 0.f);
  }
}

extern "C" void kernel_launch(void* const* d_in, const int* in_sizes, int n_in,
                              void* d_out, int out_size, void* d_ws, size_t ws_size,
                              hipStream_t stream){
  const float* in_feat   = (const float*)d_in[0];
  const float* edge_attr = (const float*)d_in[1];
  const int*   eidx      = (const int*)d_in[2];
  const int*   batch     = (const int*)d_in[3];
  const float* vn_emb    = (const float*)d_in[4];
  const float* cew = (const float*)d_in[5];
  const float* ceb = (const float*)d_in[6];
  const float* cw1 = (const float*)d_in[7];
  const float* cb1 = (const float*)d_in[8];
  const float* cw2 = (const float*)d_in[9];
  const float* cb2 = (const float*)d_in[10];
  const float* bng = (const float*)d_in[11];
  const float* bnb = (const float*)d_in[12];
  const float* vw1 = (const float*)d_in[13];
  const float* vb1 = (const float*)d_in[14];
  const float* vg1 = (const float*)d_in[15];
  const float* vbe1 = (const float*)d_in[16];
  const float* vw2 = (const float*)d_in[17];
  const float* vb2 = (const float*)d_in[18];
  const float* vg2 = (const float*)d_in[19];
  const float* vbe2 = (const float*)d_in[20];
  float* out = (float*)d_out;

  int N = in_sizes[0] / EMB;
  int E = in_sizes[2] / 2;
  const int* src = eidx;
  const int* dst = eidx + E;

  char* ws = (char*)d_ws;
  auto alloc = [&](size_t bytes) -> char* {
    char* p = ws; ws += (bytes + 255) & ~(size_t)255; return p;
  };
  ushort_t* z0    = (ushort_t*)alloc((size_t)N * EMB * 2);
  ushort_t* hb    = (ushort_t*)alloc((size_t)N * EMB * 2);
  ushort_t* ea2   = (ushort_t*)alloc((size_t)E * ED * 2);
  int*      srcs  = (int*)alloc((size_t)E * 4);
  float*    vn0   = (float*)alloc((size_t)NGRAPH * EMB * 4);
  float*    vn1   = (float*)alloc((size_t)NGRAPH * EMB * 4);
  float*    vt    = (float*)alloc((size_t)NGRAPH * EMB * 4);
  int*      counts = (int*)alloc((size_t)N * 4);
  int*      rankv  = (int*)alloc((size_t)E * 4);
  int*      offs   = (int*)alloc(((size_t)N + 1) * 4);
  int*      bsum   = (int*)alloc(256 * 4);
  int*      boff   = (int*)alloc(256 * 4);
  ushort_t* w1t = (ushort_t*)alloc((size_t)NLAYER * HID * EMB * 2);
  ushort_t* w2t = (ushort_t*)alloc((size_t)NLAYER * EMB * HID * 2);
  float* vnbuf[2] = {vn0, vn1};

  float inv = 1.0f / sqrtf(1.0f + 1e-5f);
  int ntiles = (N + 15) / 16;
  int nagg = (N + NPW * 4 - 1) / (NPW * 4);   // 4 waves/block, NPW nodes/wave

  hipMemsetAsync(counts, 0, (size_t)N * 4, stream);
  k_init_vn<<<NGRAPH * EMB / 256, 256, 0, stream>>>(vn0, vn_emb);
  k_transw<<<(NLAYER * EMB * HID + 255) / 256, 256, 0, stream>>>(cw1, cw2, w1t, w2t);
  k_count<<<(E + 255) / 256, 256, 0, stream>>>(dst, counts, rankv, E);
  int nsb = (N + 2047) / 2048;
  k_scanA<<<nsb, 256, 0, stream>>>(counts, offs, bsum, N);
  k_scanB<<<1, 256, 0, stream>>>(bsum, boff, nsb);
  k_scanC<<<(N + 1 + 255) / 256, 256, 0, stream>>>(offs, boff, N, E);
  k_reorder<<<(E + 255) / 256, 256, 0, stream>>>(edge_attr, src, dst, rankv, offs, ea2, srcs, E);

  for (int l = 0; l < NLAYER; l++){
    const float* vnc = vnbuf[l & 1];
    float* vnn = vnbuf[(l + 1) & 1];
    int last = (l == NLAYER - 1) ? 1 : 0;
    if (l == 0)
      k_hin<<<(N * 32 + 255) / 256, 256, 0, stream>>>(in_feat, batch, vnc, hb, N);
    if (!last)
      hipMemsetAsync(vt, 0, (size_t)NGRAPH * EMB * 4, stream);   // before fused atomics
    k_agg<<<nagg, 256, 0, stream>>>(hb, ea2, srcs, offs,
                                    cew + (size_t)l * ED * EMB, ceb + (size_t)l * EMB,
                                    z0, vt, batch, !last, N);
    if (!last){
      k_vnmlp<<<NGRAPH, HID, 0, stream>>>(vt,
                                          vw1 + (size_t)l * EMB * HID, vb1 + (size_t)l * HID,
                                          vg1 + (size_t)l * HID, vbe1 + (size_t)l * HID,
                                          vw2 + (size_t)l * HID * EMB, vb2 + (size_t)l * EMB,
                                          vg2 + (size_t)l * EMB, vbe2 + (size_t)l * EMB,
                                          vnc, vnn, inv);
    }
    k_mlp<<<1024, 256, 0, stream>>>(z0, w1t + (size_t)l * HID * EMB, cb1 + (size_t)l * HID,
                                    w2t + (size_t)l * EMB * HID, cb2 + (size_t)l * EMB,
                                    bng + (size_t)l * EMB, bnb + (size_t)l * EMB,
                                    hb, batch, vnn, hb, out, inv, last, ntiles, N);
  }
}

// Round 14
// 708.660 us; speedup vs baseline: 1.0234x; 1.0234x over previous
//
#include <hip/hip_runtime.h>
#include <math.h>
#include <stdint.h>

#define EMB 128
#define HID 256
#define ED 16
#define NGRAPH 512
#define NLAYER 3
#define VT_CHUNK 64
#define NPW 8            // nodes per wave in k_agg (contiguous chunk)

typedef unsigned short ushort_t;
typedef __attribute__((ext_vector_type(8))) short short8;
typedef __attribute__((ext_vector_type(4))) float fx4;
typedef __attribute__((ext_vector_type(4))) unsigned int uint4v;

__device__ __forceinline__ ushort_t f2b(float f){
  unsigned int u = __builtin_bit_cast(unsigned int, f);
  unsigned int r = u + 0x7FFFu + ((u >> 16) & 1u);
  return (ushort_t)(r >> 16);
}
__device__ __forceinline__ float b2f(ushort_t u){
  return __builtin_bit_cast(float, ((unsigned int)u) << 16);
}
__device__ __forceinline__ float blo(unsigned int u){
  return __builtin_bit_cast(float, u << 16);
}
__device__ __forceinline__ float bhi(unsigned int u){
  return __builtin_bit_cast(float, u & 0xFFFF0000u);
}

// packed bf16x2 dot with f32 accumulate: c += a.lo*b.lo + a.hi*b.hi
__device__ __forceinline__ float dot2b(unsigned int a, unsigned int b, float c){
  float r = c;
  asm("v_dot2_f32_bf16 %0, %1, %2, %0" : "+v"(r) : "v"(a), "v"(b));
  return r;
}

// 16-elem bf16 dot for two output channels from 2 packed uint4v
__device__ __forceinline__ float2 dot16(uint4v u0, uint4v u1,
                                        const unsigned int* wp0, const unsigned int* wp1,
                                        float be0, float be1){
  unsigned int uu[8] = {u0[0], u0[1], u0[2], u0[3], u1[0], u1[1], u1[2], u1[3]};
  float e0 = be0, e1 = be1;
  #pragma unroll
  for (int k = 0; k < 8; k++){
    e0 = dot2b(uu[k], wp0[k], e0);
    e1 = dot2b(uu[k], wp1[k], e1);
  }
  return make_float2(e0, e1);
}

// ---- init virtual node (broadcast vn_emb row) ----
__global__ void k_init_vn(float* __restrict__ vn, const float* __restrict__ vn_emb){
  int idx = blockIdx.x * 256 + threadIdx.x;            // NGRAPH*EMB threads
  vn[idx] = vn_emb[idx & (EMB - 1)];
}

// ---- pre-transpose MLP weights f32 -> bf16 [N][K] for MFMA B-operand ----
__global__ void k_transw(const float* __restrict__ w1, const float* __restrict__ w2,
                         ushort_t* __restrict__ w1t, ushort_t* __restrict__ w2t){
  int idx = blockIdx.x * 256 + threadIdx.x;
  if (idx >= NLAYER * EMB * HID) return;
  int l = idx / (EMB * HID);
  int r = idx % (EMB * HID);
  { int k = r / HID, n = r % HID; w1t[(l * HID + n) * EMB + k] = f2b(w1[idx]); }
  { int k = r / EMB, n = r % EMB; w2t[(l * EMB + n) * HID + k] = f2b(w2[idx]); }
}

// ---- CSR build: count + rank ----
__global__ void k_count(const int* __restrict__ dst, int* __restrict__ counts,
                        int* __restrict__ rankv, int E){
  int e = blockIdx.x * 256 + threadIdx.x;
  if (e >= E) return;
  rankv[e] = atomicAdd(&counts[dst[e]], 1);
}

// ---- 3-kernel exclusive scan over counts[N] -> offs[N] ----
__global__ void k_scanA(const int* __restrict__ counts, int* __restrict__ offs,
                        int* __restrict__ bsum, int N){
  __shared__ int sdata[256];
  int t = threadIdx.x;
  int base = blockIdx.x * 2048 + t * 8;
  int v[8]; int s = 0;
  #pragma unroll
  for (int j = 0; j < 8; j++){
    int idx = base + j;
    v[j] = (idx < N) ? counts[idx] : 0;
    s += v[j];
  }
  sdata[t] = s; __syncthreads();
  for (int off = 1; off < 256; off <<= 1){
    int x = (t >= off) ? sdata[t - off] : 0;
    __syncthreads();
    sdata[t] += x;
    __syncthreads();
  }
  int incl = sdata[t];
  int run = incl - s;   // exclusive prefix of this thread's chunk
  #pragma unroll
  for (int j = 0; j < 8; j++){
    int idx = base + j;
    if (idx < N) offs[idx] = run;
    run += v[j];
  }
  if (t == 255) bsum[blockIdx.x] = incl;
}

__global__ void k_scanB(const int* __restrict__ bsum, int* __restrict__ boff, int nb){
  __shared__ int sdata[256];
  int t = threadIdx.x;
  int v = (t < nb) ? bsum[t] : 0;
  sdata[t] = v; __syncthreads();
  for (int off = 1; off < 256; off <<= 1){
    int x = (t >= off) ? sdata[t - off] : 0;
    __syncthreads();
    sdata[t] += x;
    __syncthreads();
  }
  if (t < nb) boff[t] = sdata[t] - v;
}

__global__ void k_scanC(int* __restrict__ offs, const int* __restrict__ boff, int N, int E){
  int i = blockIdx.x * 256 + threadIdx.x;
  if (i < N) offs[i] += boff[i >> 11];
  else if (i == N) offs[N] = E;
}

// ---- CSR reorder: ea2[pos] = bf16(edge_attr[e]); srcs[pos] = src[e] ----
__global__ void k_reorder(const float* __restrict__ ea, const int* __restrict__ src,
                          const int* __restrict__ dst, const int* __restrict__ rankv,
                          const int* __restrict__ offs, ushort_t* __restrict__ ea2,
                          int* __restrict__ srcs, int E){
  int e = blockIdx.x * 256 + threadIdx.x;
  if (e >= E) return;
  int pos = offs[dst[e]] + rankv[e];
  srcs[pos] = src[e];
  const float4* p = (const float4*)(ea + (size_t)e * ED);
  float4 f0 = p[0], f1 = p[1], f2 = p[2], f3 = p[3];
  float f[ED] = {f0.x, f0.y, f0.z, f0.w, f1.x, f1.y, f1.z, f1.w,
                 f2.x, f2.y, f2.z, f2.w, f3.x, f3.y, f3.z, f3.w};
  unsigned int u[8];
  #pragma unroll
  for (int k = 0; k < 8; k++)
    u[k] = (unsigned int)f2b(f[2 * k]) | ((unsigned int)f2b(f[2 * k + 1]) << 16);
  uint4* q = (uint4*)(ea2 + (size_t)pos * ED);
  q[0] = make_uint4(u[0], u[1], u[2], u[3]);
  q[1] = make_uint4(u[4], u[5], u[6], u[7]);
}

// ---- layer-0 h_in = bf16(in_feat + vn[batch]) -> hb only ----
__global__ void k_hin(const float* __restrict__ h, const int* __restrict__ batch,
                      const float* __restrict__ vn, ushort_t* __restrict__ hb, int N){
  int idx = blockIdx.x * 256 + threadIdx.x;
  if (idx >= N * 32) return;
  int node = idx >> 5;
  int c = (idx & 31) * 4;
  float4 hv = *(const float4*)(h + (size_t)node * EMB + c);
  int b = batch[node];
  float4 v = *(const float4*)(vn + b * EMB + c);
  uint2 ob;
  ob.x = (unsigned int)f2b(hv.x + v.x) | ((unsigned int)f2b(hv.y + v.y) << 16);
  ob.y = (unsigned int)f2b(hv.z + v.z) | ((unsigned int)f2b(hv.w + v.w) << 16);
  *(uint2*)(hb + (size_t)node * EMB + c) = ob;
}

// ---- pull-style GIN aggregation (R7-proven inner loop, byte-identical):
//      contiguous NPW-node chunk per wave, flat edge stream with node-boundary
//      flush, software-pipelined (srcs 2 groups ahead, gathers 1 group ahead).
//      R14 change: 64-thread (1-wave) BLOCKS — finer workgroup granularity so
//      the scheduler packs/retires waves independently (4-wave blocks measured
//      Occupancy stuck at 38% despite VGPR=48 permitting 8 waves/SIMD).
//      No nt-loads (R3), no 2-deep pipeline (R8), no fused vt atomics (R9/R13).
//      z0 = bf16(h_in + sum_{e->node} relu(h_in[src]+edge_emb))
//      Also zeroes vt (replaces a memset launch). ----
__global__ __launch_bounds__(64) void k_agg(const ushort_t* __restrict__ hb,
                      const ushort_t* __restrict__ ea2,
                      const int* __restrict__ srcs, const int* __restrict__ offs,
                      const float* __restrict__ We, const float* __restrict__ be,
                      ushort_t* __restrict__ z0, float* __restrict__ vt,
                      int zerovt, int N){
  if (zerovt){
    int idx = blockIdx.x * 64 + threadIdx.x;
    if (idx < NGRAPH * EMB) vt[idx] = 0.f;
  }
  int lane = threadIdx.x & 63;
  int wid = blockIdx.x;                  // one wave per block
  int n0 = wid * NPW;
  if (n0 >= N) return;
  int nn = N - n0; if (nn > NPW) nn = NPW;
  int c0 = lane * 2;

  // pack edge-encoder weight columns c0, c0+1 as bf16 pairs (k-major pairs)
  unsigned int wp0[8], wp1[8];
  #pragma unroll
  for (int k = 0; k < 8; k++){
    wp0[k] = (unsigned int)f2b(We[(2 * k) * EMB + c0])
           | ((unsigned int)f2b(We[(2 * k + 1) * EMB + c0]) << 16);
    wp1[k] = (unsigned int)f2b(We[(2 * k) * EMB + c0 + 1])
           | ((unsigned int)f2b(We[(2 * k + 1) * EMB + c0 + 1]) << 16);
  }
  float be0 = be[c0], be1 = be[c0 + 1];

  int j    = offs[n0];
  int cend = offs[n0 + 1];
  int jend = offs[n0 + nn];
  int ni = 0;
  unsigned int hn = *(const unsigned int*)(hb + (size_t)n0 * EMB + c0);
  float ax = 0.f, ay = 0.f;

  // flush: when j reaches current node's end, write z0 row(s); handles empty nodes
  auto flush = [&](){
    while (j == cend && ni < nn){
      float r0 = blo(hn) + ax, r1 = bhi(hn) + ay;
      unsigned int outv = (unsigned int)f2b(r0) | ((unsigned int)f2b(r1) << 16);
      *(unsigned int*)(z0 + (size_t)(n0 + ni) * EMB + c0) = outv;
      ni++;
      if (ni < nn){
        hn = *(const unsigned int*)(hb + (size_t)(n0 + ni) * EMB + c0);
        cend = offs[n0 + ni + 1];
        ax = 0.f; ay = 0.f;
      }
    }
  };

  auto do1 = [&](unsigned int g){
    const uint4v* p = (const uint4v*)(ea2 + (size_t)j * ED);
    uint4v u0 = p[0], u1 = p[1];
    float2 m = dot16(u0, u1, wp0, wp1, be0, be1);
    ax += fmaxf(blo(g) + m.x, 0.f);
    ay += fmaxf(bhi(g) + m.y, 0.f);
    j++; flush();
  };

  auto do4 = [&](unsigned int gA, unsigned int gB, unsigned int gC, unsigned int gD){
    const uint4v* p = (const uint4v*)(ea2 + (size_t)j * ED);
    uint4v uA0 = p[0], uA1 = p[1];
    uint4v uB0 = p[2], uB1 = p[3];
    uint4v uC0 = p[4], uC1 = p[5];
    uint4v uD0 = p[6], uD1 = p[7];
    float2 mA = dot16(uA0, uA1, wp0, wp1, be0, be1);
    float2 mB = dot16(uB0, uB1, wp0, wp1, be0, be1);
    float2 mC = dot16(uC0, uC1, wp0, wp1, be0, be1);
    float2 mD = dot16(uD0, uD1, wp0, wp1, be0, be1);
    ax += fmaxf(blo(gA) + mA.x, 0.f);  ay += fmaxf(bhi(gA) + mA.y, 0.f);  j++; flush();
    ax += fmaxf(blo(gB) + mB.x, 0.f);  ay += fmaxf(bhi(gB) + mB.y, 0.f);  j++; flush();
    ax += fmaxf(blo(gC) + mC.x, 0.f);  ay += fmaxf(bhi(gC) + mC.y, 0.f);  j++; flush();
    ax += fmaxf(blo(gD) + mD.x, 0.f);  ay += fmaxf(bhi(gD) + mD.y, 0.f);  j++; flush();
  };

  flush();   // leading empty nodes

  if (j + 8 <= jend){
    // prologue: gathers for group j in flight, srcs for group j+4 in regs
    int sA = srcs[j],     sB = srcs[j + 1], sC = srcs[j + 2], sD = srcs[j + 3];
    int nA = srcs[j + 4], nB = srcs[j + 5], nC = srcs[j + 6], nD = srcs[j + 7];
    unsigned int gA = *(const unsigned int*)(hb + (size_t)sA * EMB + c0);
    unsigned int gB = *(const unsigned int*)(hb + (size_t)sB * EMB + c0);
    unsigned int gC = *(const unsigned int*)(hb + (size_t)sC * EMB + c0);
    unsigned int gD = *(const unsigned int*)(hb + (size_t)sD * EMB + c0);

    while (j + 12 <= jend){
      // current group's ea2 (consumed this iteration) — issue first
      const uint4v* p = (const uint4v*)(ea2 + (size_t)j * ED);
      uint4v uA0 = p[0], uA1 = p[1];
      uint4v uB0 = p[2], uB1 = p[3];
      uint4v uC0 = p[4], uC1 = p[5];
      uint4v uD0 = p[6], uD1 = p[7];
      // prefetch next group's gathers + next-next srcs (stay outstanding across
      // this iteration's compute)
      unsigned int hA = *(const unsigned int*)(hb + (size_t)nA * EMB + c0);
      unsigned int hB = *(const unsigned int*)(hb + (size_t)nB * EMB + c0);
      unsigned int hC = *(const unsigned int*)(hb + (size_t)nC * EMB + c0);
      unsigned int hD = *(const unsigned int*)(hb + (size_t)nD * EMB + c0);
      int tA = srcs[j + 8], tB = srcs[j + 9], tC = srcs[j + 10], tD = srcs[j + 11];
      // compute + consume current group
      float2 mA = dot16(uA0, uA1, wp0, wp1, be0, be1);
      float2 mB = dot16(uB0, uB1, wp0, wp1, be0, be1);
      float2 mC = dot16(uC0, uC1, wp0, wp1, be0, be1);
      float2 mD = dot16(uD0, uD1, wp0, wp1, be0, be1);
      ax += fmaxf(blo(gA) + mA.x, 0.f);  ay += fmaxf(bhi(gA) + mA.y, 0.f);  j++; flush();
      ax += fmaxf(blo(gB) + mB.x, 0.f);  ay += fmaxf(bhi(gB) + mB.y, 0.f);  j++; flush();
      ax += fmaxf(blo(gC) + mC.x, 0.f);  ay += fmaxf(bhi(gC) + mC.y, 0.f);  j++; flush();
      ax += fmaxf(blo(gD) + mD.x, 0.f);  ay += fmaxf(bhi(gD) + mD.y, 0.f);  j++; flush();
      gA = hA; gB = hB; gC = hC; gD = hD;
      nA = tA; nB = tB; nC = tC; nD = tD;
    }
    // drain: group at j (gathers gA..gD), then group at j+4 (srcs nA..nD)
    do4(gA, gB, gC, gD);
    gA = *(const unsigned int*)(hb + (size_t)nA * EMB + c0);
    gB = *(const unsigned int*)(hb + (size_t)nB * EMB + c0);
    gC = *(const unsigned int*)(hb + (size_t)nC * EMB + c0);
    gD = *(const unsigned int*)(hb + (size_t)nD * EMB + c0);
    do4(gA, gB, gC, gD);
  }
  while (j < jend){
    int s = srcs[j];
    unsigned int g = *(const unsigned int*)(hb + (size_t)s * EMB + c0);
    do1(g);
  }
}

// ---- fused MLP (R7-proven 16-row tiles), register-resident weights,
// grid-stride, cross-tile software pipeline: next-tile A prefetched during
// GEMM1; epilogue operands prefetched before the barrier; vn gathers under
// GEMM2. __launch_bounds__(256,2): weights need 128 VGPRs — forcing 4/CU
// spills (R6); 32-row tiles also spill (R10: compiler capped 128 VGPR).
// ts stride 266 (odd word count) — R12 neutral but harmless; kept.
// v = bn(relu(z0@W1+b1)@W2+b2)(+relu) + h_in(bf16 hb) [+ vn_next[batch]]
// l<2:  write hb (bf16) only.   l==2: write d_out (f32) only. ----
__global__ __launch_bounds__(256, 2) void k_mlp(const ushort_t* __restrict__ A,
                                                const ushort_t* __restrict__ w1t,
                                                const float* __restrict__ b1,
                                                const ushort_t* __restrict__ w2t,
                                                const float* __restrict__ b2,
                                                const float* __restrict__ gamma,
                                                const float* __restrict__ beta,
                                                const ushort_t* __restrict__ hb_in,
                                                const int* __restrict__ batch,
                                                const float* __restrict__ vn_next,
                                                ushort_t* __restrict__ hb_out,
                                                float* __restrict__ fout,
                                                float inv, int last, int ntiles, int N){
  __shared__ ushort_t ts[2][16][266];   // double-buffered hidden tile, 1 barrier/tile
  int w = threadIdx.x >> 6, lane = threadIdx.x & 63;
  int m = lane & 15, q = lane >> 4;

  // ---- preload this wave's weight fragments (once per block) ----
  short8 w1f[4][4];   // [k-step][col-tile], cols w*64 + t*16 + m
  #pragma unroll
  for (int kk = 0; kk < 4; kk++)
    #pragma unroll
    for (int t = 0; t < 4; t++)
      w1f[kk][t] = *(const short8*)(w1t + (size_t)(w * 64 + t * 16 + m) * EMB + kk * 32 + q * 8);
  short8 w2f[8][2];   // cols w*32 + t*16 + m
  #pragma unroll
  for (int kk = 0; kk < 8; kk++)
    #pragma unroll
    for (int t = 0; t < 2; t++)
      w2f[kk][t] = *(const short8*)(w2t + (size_t)(w * 32 + t * 16 + m) * HID + kk * 32 + q * 8);

  float bv1[4], bv2[2], sc2[2], bt2[2];
  #pragma unroll
  for (int t = 0; t < 4; t++) bv1[t] = b1[w * 64 + t * 16 + m];
  #pragma unroll
  for (int t = 0; t < 2; t++){
    int c = w * 32 + t * 16 + m;
    bv2[t] = b2[c]; sc2[t] = gamma[c] * inv; bt2[t] = beta[c];
  }

  int tile = blockIdx.x;
  if (tile >= ntiles) return;
  // prologue: A fragments for first tile
  short8 a_cur[4];
  #pragma unroll
  for (int kk = 0; kk < 4; kk++)
    a_cur[kk] = *(const short8*)(A + (size_t)(tile * 16 + m) * EMB + kk * 32 + q * 8);

  int p = 0;
  for (; tile < ntiles; tile += gridDim.x, p ^= 1){
    int row_base = tile * 16;
    // ---- GEMM1: [16,128] @ [128,256] -> hidden tile (LDS) ----
    fx4 acc[4];
    #pragma unroll
    for (int t = 0; t < 4; t++) acc[t] = fx4{0.f, 0.f, 0.f, 0.f};
    #pragma unroll
    for (int kk = 0; kk < 4; kk++){
      #pragma unroll
      for (int t = 0; t < 4; t++)
        acc[t] = __builtin_amdgcn_mfma_f32_16x16x32_bf16(a_cur[kk], w1f[kk][t], acc[t], 0, 0, 0);
    }
    // prefetch next tile's A fragments (hidden under LDS write + barrier + GEMM2)
    {
      int nt = tile + gridDim.x;
      int nb = (nt < ntiles) ? nt * 16 : 0;
      #pragma unroll
      for (int kk = 0; kk < 4; kk++)
        a_cur[kk] = *(const short8*)(A + (size_t)(nb + m) * EMB + kk * 32 + q * 8);
    }
    // prefetch epilogue operands (independent of LDS)
    int b_r[4]; ushort_t h_r[4][2];
    #pragma unroll
    for (int i = 0; i < 4; i++){
      int r = row_base + q * 4 + i;
      if (r >= N) r = N - 1;            // safety clamp (no-op when N % 16 == 0)
      b_r[i] = last ? 0 : batch[r];
      #pragma unroll
      for (int t = 0; t < 2; t++)
        h_r[i][t] = hb_in[(size_t)r * EMB + w * 32 + t * 16 + m];
    }
    #pragma unroll
    for (int t = 0; t < 4; t++){
      int c = w * 64 + t * 16 + m;
      #pragma unroll
      for (int i = 0; i < 4; i++)
        ts[p][q * 4 + i][c] = f2b(fmaxf(acc[t][i] + bv1[t], 0.f));
    }
    __syncthreads();
    // vn gathers issued now, consumed after GEMM2
    float vnv[4][2];
    if (!last){
      #pragma unroll
      for (int i = 0; i < 4; i++)
        #pragma unroll
        for (int t = 0; t < 2; t++)
          vnv[i][t] = vn_next[b_r[i] * EMB + w * 32 + t * 16 + m];
    }
    // ---- GEMM2: [16,256] @ [256,128] + epilogue ----
    fx4 acc2[2];
    #pragma unroll
    for (int t = 0; t < 2; t++) acc2[t] = fx4{0.f, 0.f, 0.f, 0.f};
    #pragma unroll
    for (int kk = 0; kk < 8; kk++){
      short8 a = *(const short8*)(&ts[p][m][kk * 32 + q * 8]);
      #pragma unroll
      for (int t = 0; t < 2; t++)
        acc2[t] = __builtin_amdgcn_mfma_f32_16x16x32_bf16(a, w2f[kk][t], acc2[t], 0, 0, 0);
    }
    #pragma unroll
    for (int i = 0; i < 4; i++){
      int r = row_base + q * 4 + i;
      if (r >= N) continue;             // safety (no-op when N % 16 == 0)
      #pragma unroll
      for (int t = 0; t < 2; t++){
        int c = w * 32 + t * 16 + m;
        float v = acc2[t][i] + bv2[t];
        v = v * sc2[t] + bt2[t];
        if (!last) v = fmaxf(v, 0.f);                       // inner-layer relu
        v += b2f(h_r[i][t]);                                // residual (prefetched)
        if (!last){
          v += vnv[i][t];                                   // next layer's vn add
          hb_out[(size_t)r * EMB + c] = f2b(v);
        } else {
          fout[(size_t)r * EMB + c] = v;
        }
      }
    }
  }
}

// ---- vt += segment_sum(hb, batch): chunked partial sums + boundary atomics ----
__global__ void k_vt(const ushort_t* __restrict__ hb, const int* __restrict__ batch,
                     float* __restrict__ vt, int N){
  int c = threadIdx.x & 127;
  int half = threadIdx.x >> 7;
  int start = blockIdx.x * VT_CHUNK;
  int end = start + VT_CHUNK; if (end > N) end = N;
  float acc = 0.f;
  int curg = batch[start];
  for (int i = start + half; i < end; i += 2){
    int g = batch[i];                       // wave-uniform
    if (g != curg){
      atomicAdd(&vt[curg * EMB + c], acc);
      acc = 0.f;
      curg = g;
    }
    acc += b2f(hb[(size_t)i * EMB + c]);
  }
  atomicAdd(&vt[curg * EMB + c], acc);
}

// ---- vn MLP: vn_next = vn_cur + relu(bn1(relu(bn0((vt+vn)@w1+b1))@w2+b2)) ----
__global__ void k_vnmlp(const float* __restrict__ vt,
                        const float* __restrict__ w1, const float* __restrict__ b1,
                        const float* __restrict__ g1, const float* __restrict__ be1,
                        const float* __restrict__ w2, const float* __restrict__ b2,
                        const float* __restrict__ g2, const float* __restrict__ be2,
                        const float* __restrict__ vnc, float* __restrict__ vnn, float inv){
  __shared__ float vs[EMB];
  __shared__ float ms[HID];
  int g = blockIdx.x, t = threadIdx.x;   // 256 threads
  if (t < EMB) vs[t] = vt[g * EMB + t] + vnc[g * EMB + t];
  __syncthreads();
  float acc = b1[t];
  #pragma unroll 4
  for (int k = 0; k < EMB; k++) acc = fmaf(vs[k], w1[k * HID + t], acc);
  acc = acc * (g1[t] * inv) + be1[t];
  ms[t] = fmaxf(acc, 0.f);
  __syncthreads();
  if (t < EMB){
    float a2 = b2[t];
    #pragma unroll 4
    for (int k = 0; k < HID; k++) a2 = fmaf(ms[k], w2[k * EMB + t], a2);
    a2 = a2 * (g2[t] * inv) + be2[t];
    vnn[g * EMB + t] = vnc[g * EMB + t] + fmaxf(a2, 0.f);
  }
}

extern "C" void kernel_launch(void* const* d_in, const int* in_sizes, int n_in,
                              void* d_out, int out_size, void* d_ws, size_t ws_size,
                              hipStream_t stream){
  const float* in_feat   = (const float*)d_in[0];
  const float* edge_attr = (const float*)d_in[1];
  const int*   eidx      = (const int*)d_in[2];
  const int*   batch     = (const int*)d_in[3];
  const float* vn_emb    = (const float*)d_in[4];
  const float* cew = (const float*)d_in[5];
  const float* ceb = (const float*)d_in[6];
  const float* cw1 = (const float*)d_in[7];
  const float* cb1 = (const float*)d_in[8];
  const float* cw2 = (const float*)d_in[9];
  const float* cb2 = (const float*)d_in[10];
  const float* bng = (const float*)d_in[11];
  const float* bnb = (const float*)d_in[12];
  const float* vw1 = (const float*)d_in[13];
  const float* vb1 = (const float*)d_in[14];
  const float* vg1 = (const float*)d_in[15];
  const float* vbe1 = (const float*)d_in[16];
  const float* vw2 = (const float*)d_in[17];
  const float* vb2 = (const float*)d_in[18];
  const float* vg2 = (const float*)d_in[19];
  const float* vbe2 = (const float*)d_in[20];
  float* out = (float*)d_out;

  int N = in_sizes[0] / EMB;
  int E = in_sizes[2] / 2;
  const int* src = eidx;
  const int* dst = eidx + E;

  char* ws = (char*)d_ws;
  auto alloc = [&](size_t bytes) -> char* {
    char* p = ws; ws += (bytes + 255) & ~(size_t)255; return p;
  };
  ushort_t* z0    = (ushort_t*)alloc((size_t)N * EMB * 2);
  ushort_t* hb    = (ushort_t*)alloc((size_t)N * EMB * 2);
  ushort_t* ea2   = (ushort_t*)alloc((size_t)E * ED * 2);
  int*      srcs  = (int*)alloc((size_t)E * 4);
  float*    vn0   = (float*)alloc((size_t)NGRAPH * EMB * 4);
  float*    vn1   = (float*)alloc((size_t)NGRAPH * EMB * 4);
  float*    vt    = (float*)alloc((size_t)NGRAPH * EMB * 4);
  int*      counts = (int*)alloc((size_t)N * 4);
  int*      rankv  = (int*)alloc((size_t)E * 4);
  int*      offs   = (int*)alloc(((size_t)N + 1) * 4);
  int*      bsum   = (int*)alloc(256 * 4);
  int*      boff   = (int*)alloc(256 * 4);
  ushort_t* w1t = (ushort_t*)alloc((size_t)NLAYER * HID * EMB * 2);
  ushort_t* w2t = (ushort_t*)alloc((size_t)NLAYER * EMB * HID * 2);
  float* vnbuf[2] = {vn0, vn1};

  float inv = 1.0f / sqrtf(1.0f + 1e-5f);
  int ntiles = (N + 15) / 16;
  int nagg = (N + NPW - 1) / NPW;            // 1 wave/block, NPW nodes/wave

  hipMemsetAsync(counts, 0, (size_t)N * 4, stream);
  k_init_vn<<<NGRAPH * EMB / 256, 256, 0, stream>>>(vn0, vn_emb);
  k_transw<<<(NLAYER * EMB * HID + 255) / 256, 256, 0, stream>>>(cw1, cw2, w1t, w2t);
  k_count<<<(E + 255) / 256, 256, 0, stream>>>(dst, counts, rankv, E);
  int nsb = (N + 2047) / 2048;
  k_scanA<<<nsb, 256, 0, stream>>>(counts, offs, bsum, N);
  k_scanB<<<1, 256, 0, stream>>>(bsum, boff, nsb);
  k_scanC<<<(N + 1 + 255) / 256, 256, 0, stream>>>(offs, boff, N, E);
  k_reorder<<<(E + 255) / 256, 256, 0, stream>>>(edge_attr, src, dst, rankv, offs, ea2, srcs, E);

  for (int l = 0; l < NLAYER; l++){
    const float* vnc = vnbuf[l & 1];
    float* vnn = vnbuf[(l + 1) & 1];
    int last = (l == NLAYER - 1) ? 1 : 0;
    if (l == 0)
      k_hin<<<(N * 32 + 255) / 256, 256, 0, stream>>>(in_feat, batch, vnc, hb, N);
    k_agg<<<nagg, 64, 0, stream>>>(hb, ea2, srcs, offs,
                                   cew + (size_t)l * ED * EMB, ceb + (size_t)l * EMB,
                                   z0, vt, !last, N);
    if (!last){
      k_vt<<<(N + VT_CHUNK - 1) / VT_CHUNK, 256, 0, stream>>>(hb, batch, vt, N);
      k_vnmlp<<<NGRAPH, HID, 0, stream>>>(vt,
                                          vw1 + (size_t)l * EMB * HID, vb1 + (size_t)l * HID,
                                          vg1 + (size_t)l * HID, vbe1 + (size_t)l * HID,
                                          vw2 + (size_t)l * HID * EMB, vb2 + (size_t)l * EMB,
                                          vg2 + (size_t)l * EMB, vbe2 + (size_t)l * EMB,
                                          vnc, vnn, inv);
    }
    k_mlp<<<1024, 256, 0, stream>>>(z0, w1t + (size_t)l * HID * EMB, cb1 + (size_t)l * HID,
                                    w2t + (size_t)l * EMB * HID, cb2 + (size_t)l * EMB,
                                    bng + (size_t)l * EMB, bnb + (size_t)l * EMB,
                                    hb, batch, vnn, hb, out, inv, last, ntiles, N);
  }
}